// Round 11
// baseline (368.893 us; speedup 1.0000x reference)
//
#include <hip/hip_runtime.h>
#include <hip/hip_bf16.h>
#include <math.h>

#define B_ROWS 1024
#define NT 8192
#define NS 8192
#define DIM 1024
#define NC 10
#define TEMP 100.0f
#define WCAP 1024   // sparse weight list capacity (selected weights)
#define CCAP 512    // per-row candidate capacity (expect ~128-256)
#define LTHR 18.421681f  // ln(1e8): candidate threshold below block-row max
#define PREP_RPB 8  // rows per block in k_prep0
#define TSTR 132    // logit tile row stride (floats)

typedef __bf16 bf16x8 __attribute__((ext_vector_type(8)));
typedef __bf16 bf16x4 __attribute__((ext_vector_type(4)));
typedef float f32x4 __attribute__((ext_vector_type(4)));

#define GLOAD_LDS(g, l) \
    __builtin_amdgcn_global_load_lds((__attribute__((address_space(1))) void*)(g), \
                                     (__attribute__((address_space(3))) void*)(l), 16, 0, 0)

__device__ inline __bf16 split_hi(float v) { return (__bf16)v; }
__device__ inline __bf16 split_lo(float v) {
    __bf16 h = (__bf16)v;
    return (__bf16)(v - (float)h);
}

// ---------------- reduction helpers ----------------
__device__ inline float wave_max(float v) {
    #pragma unroll
    for (int off = 32; off > 0; off >>= 1)
        v = fmaxf(v, __shfl_down(v, off, 64));
    return v;
}
__device__ inline float wave_sum(float v) {
    #pragma unroll
    for (int off = 32; off > 0; off >>= 1)
        v += __shfl_down(v, off, 64);
    return v;
}
__device__ inline float max4(float4 v) {
    return fmaxf(fmaxf(v.x, v.y), fmaxf(v.z, v.w));
}

// ---- K0: conv_norm(x|tf|sf) 8 rows/block + prep_labels + zero cnt/done -----
__global__ __launch_bounds__(256) void k_prep0(const float* __restrict__ x,
                                               const float* __restrict__ tf,
                                               const float* __restrict__ sf,
                                               const float* __restrict__ sld,
                                               const float* __restrict__ shdl,
                                               const float* __restrict__ atl,
                                               __bf16* __restrict__ x2,
                                               __bf16* __restrict__ tf2,
                                               __bf16* __restrict__ sf2,
                                               float* __restrict__ nx_,
                                               float* __restrict__ nt_,
                                               float* __restrict__ ns_,
                                               float* __restrict__ M2Tt,
                                               float* __restrict__ atlt,
                                               int* __restrict__ cnt,
                                               int* __restrict__ done2) {
    __shared__ float sred[4][PREP_RPB];
    __shared__ float sldL[NC * NC];
    const int NXB = B_ROWS / PREP_RPB;   // 128
    const int NTB = NT / PREP_RPB;       // 1024
    const int NSB = NS / PREP_RPB;       // 1024
    int b = blockIdx.x;
    int tid = threadIdx.x;
    if (b < NXB + NTB + NSB) {
        const float* Xp; __bf16* X2p; float* np; int r0;
        if (b < NXB)            { Xp = x;  X2p = x2;  np = nx_; r0 = b * PREP_RPB; }
        else if (b < NXB + NTB) { Xp = tf; X2p = tf2; np = nt_; r0 = (b - NXB) * PREP_RPB; }
        else                    { Xp = sf; X2p = sf2; np = ns_; r0 = (b - NXB - NTB) * PREP_RPB; }
        int c = tid * 4;
        int lane = tid & 63, wid = tid >> 6;
        #pragma unroll
        for (int r = 0; r < PREP_RPB; r++) {
            float4 v = *(const float4*)(Xp + (size_t)(r0 + r) * DIM + c);
            bf16x4 h, l;
            h[0] = split_hi(v.x); l[0] = split_lo(v.x);
            h[1] = split_hi(v.y); l[1] = split_lo(v.y);
            h[2] = split_hi(v.z); l[2] = split_lo(v.z);
            h[3] = split_hi(v.w); l[3] = split_lo(v.w);
            *(bf16x4*)(X2p + (size_t)(r0 + r) * 2048 + c) = h;
            *(bf16x4*)(X2p + (size_t)(r0 + r) * 2048 + 1024 + c) = l;
            float acc = v.x * v.x + v.y * v.y + v.z * v.z + v.w * v.w;
            float w = wave_sum(acc);
            if (lane == 0) sred[wid][r] = w;
        }
        __syncthreads();
        if (tid < PREP_RPB)
            np[r0 + tid] = sred[0][tid] + sred[1][tid] + sred[2][tid] + sred[3][tid];
    } else {
        if (b == NXB + NTB + NSB) {      // first label block zeroes counters
            #pragma unroll
            for (int z = 0; z < 4; z++) cnt[tid + z * 256] = 0;
            if (tid < 8) done2[tid] = 0;
        }
        if (tid < NC * NC) sldL[tid] = sld[tid];
        __syncthreads();
        int j = (b - NXB - NTB - NSB) * 256 + tid;
        float sh[NC], at[NC];
        #pragma unroll
        for (int k = 0; k < NC; k++) sh[k] = shdl[(size_t)j * NC + k];
        #pragma unroll
        for (int c = 0; c < NC; c++) at[c] = atl[(size_t)j * NC + c];
        #pragma unroll
        for (int c = 0; c < NC; c++) {
            float t = 0.f;
            #pragma unroll
            for (int k = 0; k < NC; k++) t += sldL[c * NC + k] * sh[k];
            M2Tt[c * NS + j] = t;
            atlt[c * NS + j] = at[c];
        }
    }
}

// ---- G1 kernel: partial softmax stats + candidates, LDS-tile epilogue ------
// (r10-verified, 65us). Per row r, col-block b: ms[r][b]=(m_b,s_b);
// candidates: l > m_b - ln(1e8) (superset of true weights > 1e-8).
__global__ __launch_bounds__(512, 4) void k_gemm_part(const __bf16* __restrict__ A2,
                                                      const __bf16* __restrict__ B2,
                                                      int N, int K,
                                                      const float* __restrict__ rowN,
                                                      const float* __restrict__ colN,
                                                      float2* __restrict__ ms,
                                                      int* __restrict__ cnt,
                                                      int* __restrict__ candj,
                                                      float* __restrict__ candl) {
    __shared__ union {
        struct { unsigned short Ah[8192], Al[8192], Bh[8192], Bl[8192]; } st;
        float tile[128 * TSTR];
    } U;
    __shared__ float extraL[256];
    float* rnL = extraL;
    float* cnL = extraL + 128;

    int tid = threadIdx.x;
    int wid = tid >> 6, lane = tid & 63;
    int wm = (wid >> 2) * 64, wn = (wid & 3) * 32;
    int id = blockIdx.y * gridDim.x + blockIdx.x;
    int bn_i = ((id >> 6) << 3) | (id & 7);
    int bm_i = (id >> 3) & 7;
    int bm = bm_i * 128, bn = bn_i * 128;
    size_t K2 = 2 * (size_t)K;
    int nsteps = K >> 6;

    if (tid < 128) rnL[tid] = rowN[bm + tid];
    else if (tid < 256) cnL[tid - 128] = colN[bn + tid - 128];

    f32x4 acc[4][2];
    #pragma unroll
    for (int i = 0; i < 4; i++)
        #pragma unroll
        for (int j = 0; j < 2; j++) acc[i][j] = (f32x4){0.f, 0.f, 0.f, 0.f};

    int arr = wid & 3, hh = wid >> 2;
    char* arrB = (arr == 0) ? (char*)U.st.Ah : (arr == 1) ? (char*)U.st.Al
               : (arr == 2) ? (char*)U.st.Bh : (char*)U.st.Bl;
    const __bf16* gbase = (arr < 2) ? A2 : B2;
    int rbase = (arr < 2) ? bm : bn;
    int hilo = (arr & 1) ? K : 0;
    int r_in = lane >> 3;
    int cgo = ((lane & 7) ^ r_in) * 8;
    const __bf16* gw = gbase + (size_t)(rbase + hh * 64 + r_in) * K2 + hilo + cgo;
    int ldst = hh * 8192;
    size_t row8 = 8 * K2;

    int ra = lane & 15, q = lane >> 4;
    int aoff[4][2], boff[2][2];
    #pragma unroll
    for (int kh = 0; kh < 2; kh++) {
        #pragma unroll
        for (int i = 0; i < 4; i++) {
            int chunk = ((kh << 2) | q) ^ (ra & 7);
            aoff[i][kh] = (wm + i * 16 + ra) * 64 + chunk * 8;
        }
        #pragma unroll
        for (int j = 0; j < 2; j++) {
            int chunk = ((kh << 2) | q) ^ (ra & 7);
            boff[j][kh] = (wn + j * 16 + ra) * 64 + chunk * 8;
        }
    }
    const __bf16* AhE = (const __bf16*)U.st.Ah;
    const __bf16* AlE = (const __bf16*)U.st.Al;
    const __bf16* BhE = (const __bf16*)U.st.Bh;
    const __bf16* BlE = (const __bf16*)U.st.Bl;

    for (int ks = 0; ks < nsteps; ks++) {
        __syncthreads();
        #pragma unroll
        for (int p = 0; p < 8; p++)
            GLOAD_LDS(gw + (size_t)p * row8, arrB + ldst + p * 1024);
        gw += 64;
        __syncthreads();
        #pragma unroll
        for (int kh = 0; kh < 2; kh++) {
            bf16x8 ah[4], al[4];
            #pragma unroll
            for (int mi = 0; mi < 4; mi++) {
                ah[mi] = *(const bf16x8*)(AhE + aoff[mi][kh]);
                al[mi] = *(const bf16x8*)(AlE + aoff[mi][kh]);
            }
            #pragma unroll
            for (int ni = 0; ni < 2; ni++) {
                bf16x8 bh = *(const bf16x8*)(BhE + boff[ni][kh]);
                bf16x8 bl = *(const bf16x8*)(BlE + boff[ni][kh]);
                #pragma unroll
                for (int mi = 0; mi < 4; mi++) {
                    acc[mi][ni] = __builtin_amdgcn_mfma_f32_16x16x32_bf16(ah[mi], bh, acc[mi][ni], 0, 0, 0);
                    acc[mi][ni] = __builtin_amdgcn_mfma_f32_16x16x32_bf16(ah[mi], bl, acc[mi][ni], 0, 0, 0);
                    acc[mi][ni] = __builtin_amdgcn_mfma_f32_16x16x32_bf16(al[mi], bh, acc[mi][ni], 0, 0, 0);
                }
            }
        }
    }

    // ---- epilogue: acc -> LDS logit tile (staging arrays now dead) ----
    __syncthreads();
    #pragma unroll
    for (int mi = 0; mi < 4; mi++) {
        #pragma unroll
        for (int ni = 0; ni < 2; ni++) {
            int cl = wn + ni * 16 + ra;
            float cn = cnL[cl];
            #pragma unroll
            for (int i = 0; i < 4; i++) {
                int rl = wm + mi * 16 + q * 4 + i;
                float sq = rnL[rl] + cn - 2.f * acc[mi][ni][i];
                U.tile[rl * TSTR + cl] = -TEMP * sqrtf(fmaxf(sq, 1e-12f));
            }
        }
    }
    __syncthreads();

    // ---- row scan: thread t -> row t>>2, quarter t&3 (32 cols) ----
    int r = tid >> 2, qt = tid & 3;
    const float4* rowp = (const float4*)&U.tile[r * TSTR + qt * 32];
    float4 v[8];
    float m = -1e30f;
    #pragma unroll
    for (int k = 0; k < 8; k++) {
        v[k] = rowp[k];
        m = fmaxf(m, max4(v[k]));
    }
    m = fmaxf(m, __shfl_xor(m, 1, 64));
    m = fmaxf(m, __shfl_xor(m, 2, 64));
    float s = 0.f;
    #pragma unroll
    for (int k = 0; k < 8; k++) {
        s += __expf(v[k].x - m) + __expf(v[k].y - m)
           + __expf(v[k].z - m) + __expf(v[k].w - m);
    }
    s += __shfl_xor(s, 1, 64);
    s += __shfl_xor(s, 2, 64);
    int gr = bm + r;
    if (qt == 0) ms[(size_t)gr * 64 + bn_i] = make_float2(m, s);
    float thr = m - LTHR;
    #pragma unroll
    for (int k = 0; k < 8; k++) {
        #pragma unroll
        for (int e = 0; e < 4; e++) {
            float lv = (e == 0) ? v[k].x : (e == 1) ? v[k].y : (e == 2) ? v[k].z : v[k].w;
            if (lv > thr) {
                int kk = atomicAdd(&cnt[gr], 1);
                if (kk < CCAP) {
                    candj[(size_t)gr * CCAP + kk] = bn + qt * 32 + k * 4 + e;
                    candl[(size_t)gr * CCAP + kk] = lv;
                }
            }
        }
    }
}

// ---- k_xsrc: exact softmax from partials + candidate eval + sparse gather --
__global__ __launch_bounds__(256) void k_xsrc(const float2* __restrict__ ms,
                                              const int* __restrict__ cnt,
                                              const int* __restrict__ candj,
                                              const float* __restrict__ candl,
                                              const float* __restrict__ asf,
                                              const float* __restrict__ W,
                                              const float* __restrict__ bias,
                                              __bf16* __restrict__ xsrc2,
                                              float* __restrict__ nx2_,
                                              float* __restrict__ preds) {
    __shared__ float sm[4];
    __shared__ float ss[4];
    __shared__ int   sidx[WCAP];
    __shared__ float swt[WCAP];
    __shared__ int   scnt;
    __shared__ float red[4][NC + 1];
    int row = blockIdx.x;
    int tid = threadIdx.x;
    int lane = tid & 63, wid = tid >> 6;
    if (tid == 0) scnt = 0;
    float2 msv = ms[(size_t)row * 64 + lane];
    float wmx = wave_max(msv.x);
    if (lane == 0) sm[wid] = wmx;
    __syncthreads();                     // also covers scnt=0
    float M = fmaxf(fmaxf(sm[0], sm[1]), fmaxf(sm[2], sm[3]));
    float sp = msv.y * __expf(msv.x - M);
    float wsv = wave_sum(sp);
    if (lane == 0) ss[wid] = wsv;
    __syncthreads();
    float inv = 1.0f / ss[0];
    int n = cnt[row]; n = n < CCAP ? n : CCAP;
    for (int i = tid; i < n; i += 256) {
        float w = __expf(candl[(size_t)row * CCAP + i] - M) * inv;
        if (w > 1e-8f) {
            int k = atomicAdd(&scnt, 1);
            if (k < WCAP) { sidx[k] = candj[(size_t)row * CCAP + i]; swt[k] = w; }
        }
    }
    __syncthreads();
    int cw = scnt < WCAP ? scnt : WCAP;
    int c = tid * 4;
    float sx = 0.f, sy = 0.f, sz = 0.f, sw = 0.f;
    for (int i = 0; i < cw; i++) {
        float wg = swt[i];
        float4 v = *(const float4*)(asf + (size_t)sidx[i] * DIM + c);
        sx += wg * v.x; sy += wg * v.y; sz += wg * v.z; sw += wg * v.w;
    }
    bf16x4 h, l;
    h[0] = split_hi(sx); l[0] = split_lo(sx);
    h[1] = split_hi(sy); l[1] = split_lo(sy);
    h[2] = split_hi(sz); l[2] = split_lo(sz);
    h[3] = split_hi(sw); l[3] = split_lo(sw);
    *(bf16x4*)(xsrc2 + (size_t)row * 2048 + c) = h;
    *(bf16x4*)(xsrc2 + (size_t)row * 2048 + 1024 + c) = l;
    float accn = sx * sx + sy * sy + sz * sz + sw * sw;
    float accp[NC];
    #pragma unroll
    for (int cc = 0; cc < NC; cc++)
        accp[cc] = sx * W[(c + 0) * NC + cc] + sy * W[(c + 1) * NC + cc]
                 + sz * W[(c + 2) * NC + cc] + sw * W[(c + 3) * NC + cc];
    accn = wave_sum(accn);
    #pragma unroll
    for (int cc = 0; cc < NC; cc++) accp[cc] = wave_sum(accp[cc]);
    if (lane == 0) {
        red[wid][0] = accn;
        #pragma unroll
        for (int cc = 0; cc < NC; cc++) red[wid][1 + cc] = accp[cc];
    }
    __syncthreads();
    if (tid == 0) {
        nx2_[row] = red[0][0] + red[1][0] + red[2][0] + red[3][0];
        float lo[NC];
        float m = -1e30f;
        #pragma unroll
        for (int cc = 0; cc < NC; cc++) {
            lo[cc] = red[0][1 + cc] + red[1][1 + cc] + red[2][1 + cc] + red[3][1 + cc]
                   + bias[cc];
            m = fmaxf(m, lo[cc]);
        }
        float ssum = 0.f;
        #pragma unroll
        for (int cc = 0; cc < NC; cc++) {
            lo[cc] = __expf(lo[cc] - m);
            ssum += lo[cc];
        }
        float iv = 1.0f / ssum;
        #pragma unroll
        for (int cc = 0; cc < NC; cc++) preds[(size_t)row * NC + cc] = lo[cc] * iv;
    }
}

// ---- G3Y: distance GEMM + FUSED label-softmax partials + last-block y merge
// Eliminates S (32MB write + 32MB read) and the k_lab dispatch entirely.
// Per (row, col-block): logits l_j = -TEMP*d - sum_c TEMP*preds[c]*M2Tt[c][j]
// computed in the LDS-tile scan; partial (m_b, s_b, Y_b[10]) written to P.
// Last block per row-group (device-scope atomic, G16 pattern) merges exactly:
//   y = sum_b e^{m_b-M} Y_b / sum_b e^{m_b-M} s_b
__global__ __launch_bounds__(512, 4) void k_gemm3Y(const __bf16* __restrict__ A2,
                                                   const __bf16* __restrict__ B2,
                                                   int N, int K,
                                                   const float* __restrict__ rowN,
                                                   const float* __restrict__ colN,
                                                   const float* __restrict__ predsG,
                                                   const float* __restrict__ M2Tt,
                                                   const float* __restrict__ atlt,
                                                   float* __restrict__ P,
                                                   int* __restrict__ done2,
                                                   float* __restrict__ y) {
    __shared__ union {
        struct { unsigned short Ah[8192], Al[8192], Bh[8192], Bl[8192]; } st;
        float tile[128 * TSTR];
    } U;
    __shared__ float extraL[256];
    __shared__ int lastF;
    float* rnL = extraL;
    float* cnL = extraL + 128;

    int tid = threadIdx.x;
    int wid = tid >> 6, lane = tid & 63;
    int wm = (wid >> 2) * 64, wn = (wid & 3) * 32;
    int id = blockIdx.y * gridDim.x + blockIdx.x;
    int bn_i = ((id >> 6) << 3) | (id & 7);
    int bm_i = (id >> 3) & 7;
    int bm = bm_i * 128, bn = bn_i * 128;
    size_t K2 = 2 * (size_t)K;
    int nsteps = K >> 6;

    if (tid < 128) rnL[tid] = rowN[bm + tid];
    else if (tid < 256) cnL[tid - 128] = colN[bn + tid - 128];

    f32x4 acc[4][2];
    #pragma unroll
    for (int i = 0; i < 4; i++)
        #pragma unroll
        for (int j = 0; j < 2; j++) acc[i][j] = (f32x4){0.f, 0.f, 0.f, 0.f};

    int arr = wid & 3, hh = wid >> 2;
    char* arrB = (arr == 0) ? (char*)U.st.Ah : (arr == 1) ? (char*)U.st.Al
               : (arr == 2) ? (char*)U.st.Bh : (char*)U.st.Bl;
    const __bf16* gbase = (arr < 2) ? A2 : B2;
    int rbase = (arr < 2) ? bm : bn;
    int hilo = (arr & 1) ? K : 0;
    int r_in = lane >> 3;
    int cgo = ((lane & 7) ^ r_in) * 8;
    const __bf16* gw = gbase + (size_t)(rbase + hh * 64 + r_in) * K2 + hilo + cgo;
    int ldst = hh * 8192;
    size_t row8 = 8 * K2;

    int ra = lane & 15, q = lane >> 4;
    int aoff[4][2], boff[2][2];
    #pragma unroll
    for (int kh = 0; kh < 2; kh++) {
        #pragma unroll
        for (int i = 0; i < 4; i++) {
            int chunk = ((kh << 2) | q) ^ (ra & 7);
            aoff[i][kh] = (wm + i * 16 + ra) * 64 + chunk * 8;
        }
        #pragma unroll
        for (int j = 0; j < 2; j++) {
            int chunk = ((kh << 2) | q) ^ (ra & 7);
            boff[j][kh] = (wn + j * 16 + ra) * 64 + chunk * 8;
        }
    }
    const __bf16* AhE = (const __bf16*)U.st.Ah;
    const __bf16* AlE = (const __bf16*)U.st.Al;
    const __bf16* BhE = (const __bf16*)U.st.Bh;
    const __bf16* BlE = (const __bf16*)U.st.Bl;

    for (int ks = 0; ks < nsteps; ks++) {
        __syncthreads();
        #pragma unroll
        for (int p = 0; p < 8; p++)
            GLOAD_LDS(gw + (size_t)p * row8, arrB + ldst + p * 1024);
        gw += 64;
        __syncthreads();
        #pragma unroll
        for (int kh = 0; kh < 2; kh++) {
            bf16x8 ah[4], al[4];
            #pragma unroll
            for (int mi = 0; mi < 4; mi++) {
                ah[mi] = *(const bf16x8*)(AhE + aoff[mi][kh]);
                al[mi] = *(const bf16x8*)(AlE + aoff[mi][kh]);
            }
            #pragma unroll
            for (int ni = 0; ni < 2; ni++) {
                bf16x8 bh = *(const bf16x8*)(BhE + boff[ni][kh]);
                bf16x8 bl = *(const bf16x8*)(BlE + boff[ni][kh]);
                #pragma unroll
                for (int mi = 0; mi < 4; mi++) {
                    acc[mi][ni] = __builtin_amdgcn_mfma_f32_16x16x32_bf16(ah[mi], bh, acc[mi][ni], 0, 0, 0);
                    acc[mi][ni] = __builtin_amdgcn_mfma_f32_16x16x32_bf16(ah[mi], bl, acc[mi][ni], 0, 0, 0);
                    acc[mi][ni] = __builtin_amdgcn_mfma_f32_16x16x32_bf16(al[mi], bh, acc[mi][ni], 0, 0, 0);
                }
            }
        }
    }

    // ---- epilogue: distance logits -> LDS tile ----
    __syncthreads();
    #pragma unroll
    for (int mi = 0; mi < 4; mi++) {
        #pragma unroll
        for (int ni = 0; ni < 2; ni++) {
            int cl = wn + ni * 16 + ra;
            float cn = cnL[cl];
            #pragma unroll
            for (int i = 0; i < 4; i++) {
                int rl = wm + mi * 16 + q * 4 + i;
                float sq = rnL[rl] + cn - 2.f * acc[mi][ni][i];
                U.tile[rl * TSTR + cl] = -TEMP * sqrtf(fmaxf(sq, 1e-12f));
            }
        }
    }
    __syncthreads();

    // ---- scan: add label cost, per-block softmax partials (m,s,Y[10]) ----
    int r = tid >> 2, qt = tid & 3;
    int gr = bm + r;
    float pr[NC];
    #pragma unroll
    for (int c = 0; c < NC; c++) pr[c] = TEMP * predsG[(size_t)gr * NC + c];
    const float4* M2 = (const float4*)M2Tt;    // [NC][2048]
    const float4* AT = (const float4*)atlt;    // [NC][2048]
    int cb = (bn >> 2) + qt * 8;
    const float4* rowp = (const float4*)&U.tile[r * TSTR + qt * 32];
    float4 v[8];
    float m = -1e30f;
    #pragma unroll
    for (int k = 0; k < 8; k++) {
        float4 sv = rowp[k];
        float4 lab = make_float4(0.f, 0.f, 0.f, 0.f);
        #pragma unroll
        for (int c = 0; c < NC; c++) {
            float4 mv = M2[(c << 11) + cb + k];
            lab.x += pr[c] * mv.x; lab.y += pr[c] * mv.y;
            lab.z += pr[c] * mv.z; lab.w += pr[c] * mv.w;
        }
        sv.x -= lab.x; sv.y -= lab.y; sv.z -= lab.z; sv.w -= lab.w;
        v[k] = sv;
        m = fmaxf(m, max4(sv));
    }
    m = fmaxf(m, __shfl_xor(m, 1, 64));
    m = fmaxf(m, __shfl_xor(m, 2, 64));
    float s = 0.f;
    float Y[NC] = {};
    #pragma unroll
    for (int k = 0; k < 8; k++) {
        float4 p;
        p.x = __expf(v[k].x - m); p.y = __expf(v[k].y - m);
        p.z = __expf(v[k].z - m); p.w = __expf(v[k].w - m);
        s += p.x + p.y + p.z + p.w;
        #pragma unroll
        for (int c = 0; c < NC; c++) {
            float4 av = AT[(c << 11) + cb + k];
            Y[c] += p.x * av.x + p.y * av.y + p.z * av.z + p.w * av.w;
        }
    }
    s += __shfl_xor(s, 1, 64);
    s += __shfl_xor(s, 2, 64);
    #pragma unroll
    for (int c = 0; c < NC; c++) {
        Y[c] += __shfl_xor(Y[c], 1, 64);
        Y[c] += __shfl_xor(Y[c], 2, 64);
    }
    if (qt == 0) {
        float* Pp = P + ((size_t)gr * 64 + bn_i) * 12;
        Pp[0] = m; Pp[1] = s;
        #pragma unroll
        for (int c = 0; c < NC; c++) Pp[2 + c] = Y[c];
    }

    // ---- last-block-per-row-group merge (device-scope, G16 pattern) ----
    __syncthreads();
    if (tid == 0) {
        __threadfence();                 // release: publish partials
        int old = atomicAdd(&done2[bm_i], 1);
        lastF = (old == 63);
    }
    __syncthreads();
    if (!lastF) return;
    __threadfence();                     // acquire: see all partials

    float mm = -1e30f;
    #pragma unroll
    for (int b = 0; b < 16; b++)
        mm = fmaxf(mm, P[((size_t)gr * 64 + qt * 16 + b) * 12]);
    mm = fmaxf(mm, __shfl_xor(mm, 1, 64));
    mm = fmaxf(mm, __shfl_xor(mm, 2, 64));
    float den = 0.f;
    float y10[NC] = {};
    #pragma unroll
    for (int b = 0; b < 16; b++) {
        const float* Pp = P + ((size_t)gr * 64 + qt * 16 + b) * 12;
        float e = __expf(Pp[0] - mm);
        den += Pp[1] * e;
        #pragma unroll
        for (int c = 0; c < NC; c++) y10[c] += Pp[2 + c] * e;
    }
    den += __shfl_xor(den, 1, 64);
    den += __shfl_xor(den, 2, 64);
    #pragma unroll
    for (int c = 0; c < NC; c++) {
        y10[c] += __shfl_xor(y10[c], 1, 64);
        y10[c] += __shfl_xor(y10[c], 2, 64);
    }
    if (qt == 0) {
        float invd = 1.0f / den;
        #pragma unroll
        for (int c = 0; c < NC; c++) y[(size_t)gr * NC + c] = y10[c] * invd;
    }
}

extern "C" void kernel_launch(void* const* d_in, const int* in_sizes, int n_in,
                              void* d_out, int out_size, void* d_ws, size_t ws_size,
                              hipStream_t stream) {
    const float* x    = (const float*)d_in[0];   // [1024, 32, 32]
    const float* tf   = (const float*)d_in[1];   // [8192, 1024]
    const float* asf  = (const float*)d_in[2];   // [8192, 1024]
    const float* sf   = (const float*)d_in[3];   // [8192, 1024]
    const float* shdl = (const float*)d_in[4];   // [8192, 10]
    const float* atl  = (const float*)d_in[5];   // [8192, 10]
    const float* sld  = (const float*)d_in[6];   // [10, 10]
    const float* W    = (const float*)d_in[7];   // [1024, 10]
    const float* bias = (const float*)d_in[8];   // [10]
    float* y = (float*)d_out;                    // [1024, 10]

    char* wsb = (char*)d_ws;
    // Region lifetimes (S fully eliminated):
    //  R0 @0: [G1/xsrc phase] candj(2M) candl(2M) ms(512K) cnt(4K) done2(32B)
    //         [G3 phase]      P partials (3MB @ 8MB offset)
    //  R1 @32 (32 MiB): tf2 (dead after G1)
    //  R2 @64 (32 MiB): sf2 (written by k_prep0, read by G3)
    int*    candj = (int*)(wsb);
    float*  candl = (float*)(wsb + (2u << 20));
    float2* ms    = (float2*)(wsb + (4u << 20));
    int*    cnt   = (int*)(wsb + (4u << 20) + (512u << 10));
    int*    done2 = cnt + B_ROWS;
    float*  P     = (float*)(wsb + (8u << 20));             // [1024][64][12]
    __bf16* tf2   = (__bf16*)(wsb + (32u << 20));
    __bf16* sf2   = (__bf16*)(wsb + (64u << 20));
    __bf16* x2    = (__bf16*)(wsb + (96u << 20));           // 4 MiB
    __bf16* xsrc2 = (__bf16*)(wsb + (100u << 20));          // 4 MiB
    float*  nt_   = (float*)(wsb + (108u << 20));
    float*  ns_   = nt_ + NT;
    float*  nx_   = ns_ + NS;
    float*  nx2_  = nx_ + B_ROWS;
    float*  preds = nx2_ + B_ROWS;
    float*  M2Tt  = preds + B_ROWS * NC;                    // [10][8192]
    float*  atlt  = M2Tt + NS * NC;                         // [10][8192]

    // K0: conv_norm(x|tf|sf) + prep_labels + zero cnt/done2
    {
        int nblk = B_ROWS / PREP_RPB + NT / PREP_RPB + NS / PREP_RPB + NS / 256;
        k_prep0<<<nblk, 256, 0, stream>>>(x, tf, sf, sld, shdl, atl,
                                          x2, tf2, sf2, nx_, nt_, ns_, M2Tt, atlt,
                                          cnt, done2);
    }

    // G1 (partial): per-block softmax stats + candidates; no S materialization
    {
        dim3 g(NT / 128, B_ROWS / 128, 1);
        k_gemm_part<<<g, 512, 0, stream>>>(x2, tf2, NT, DIM, nx_, nt_,
                                           ms, cnt, candj, candl);
    }

    // k_xsrc: exact softmax merge + sparse gather
    k_xsrc<<<B_ROWS, 256, 0, stream>>>(ms, cnt, candj, candl, asf, W, bias,
                                       xsrc2, nx2_, preds);

    // G3Y: distance GEMM + fused label softmax partials + last-block y merge
    {
        dim3 g(NS / 128, B_ROWS / 128, 1);
        k_gemm3Y<<<g, 512, 0, stream>>>(xsrc2, sf2, NS, DIM, nx2_, ns_,
                                        preds, M2Tt, atlt, P, done2, y);
    }
}